// Round 4
// baseline (1268.921 us; speedup 1.0000x reference)
//
#include <hip/hip_runtime.h>
#include <hip/hip_fp16.h>
#include <math.h>

#define H 128
#define BSTRIDE 5120            // packed entries per bucket (mean 4096, +16 sigma)

typedef float f32x4_t __attribute__((ext_vector_type(4)));

// ---------------- CSR build: bucketed counting sort ----------------
// bucket = dst >> 7 (128 nodes per bucket). packed entry = (local_dst<<17)|src.

__global__ __launch_bounds__(256) void bin_kernel(const int* __restrict__ src,
        const int* __restrict__ dst, int* __restrict__ bucketFill,
        int* __restrict__ packed, int E, int nbk) {
    __shared__ int hcnt[1024];
    __shared__ int base[1024];
    __shared__ int cur[1024];
    int tid = threadIdx.x;
    for (int i = tid; i < nbk; i += 256) { hcnt[i] = 0; cur[i] = 0; }
    __syncthreads();
    int e0 = blockIdx.x * 8192;
    int e1 = min(e0 + 8192, E);
    for (int e = e0 + tid; e < e1; e += 256)
        atomicAdd(&hcnt[dst[e] >> 7], 1);
    __syncthreads();
    for (int i = tid; i < nbk; i += 256) {
        int c = hcnt[i];
        base[i] = c ? atomicAdd(&bucketFill[i], c) : 0;   // claim contiguous chunk
    }
    __syncthreads();
    for (int e = e0 + tid; e < e1; e += 256) {
        int d = dst[e], s = src[e];
        int b = d >> 7;
        int r = atomicAdd(&cur[b], 1);
        packed[b * BSTRIDE + base[b] + r] = ((d & 127) << 17) | s;
    }
}

__global__ void bscan_kernel(const int* __restrict__ bucketFill, int* __restrict__ bucketBase,
                             int nbk, int E, int* __restrict__ rowptrN) {
    __shared__ int s[1024];
    int t = threadIdx.x;
    int v0 = (t < nbk) ? bucketFill[t] : 0;
    s[t] = v0;
    __syncthreads();
    for (int off = 1; off < 1024; off <<= 1) {
        int v = 0;
        if (t >= off) v = s[t - off];
        __syncthreads();
        s[t] += v;
        __syncthreads();
    }
    bucketBase[t] = s[t] - v0;                 // exclusive
    if (t == 0) rowptrN[0] = E;                // rowptr[N] = E
}

__global__ __launch_bounds__(256) void fine_kernel(const int* __restrict__ packed,
        const int* __restrict__ bucketFill, const int* __restrict__ bucketBase,
        int* __restrict__ rowptr, int* __restrict__ col, float* __restrict__ dinv, int N) {
    __shared__ int lcnt[128], lofs[128], lcur[128];
    int b = blockIdx.x;
    int tid = threadIdx.x;
    int m = bucketFill[b]; if (m > BSTRIDE) m = BSTRIDE;
    int base = bucketBase[b];
    int n0 = b << 7;
    if (tid < 128) lcnt[tid] = 0;
    __syncthreads();
    const int* pk = packed + (size_t)b * BSTRIDE;
    for (int i = tid; i < m; i += 256) atomicAdd(&lcnt[pk[i] >> 17], 1);
    __syncthreads();
    if (tid == 0) {
        int acc = 0;
        #pragma unroll 4
        for (int i = 0; i < 128; ++i) { lofs[i] = acc; acc += lcnt[i]; }
    }
    __syncthreads();
    if (tid < 128) {
        lcur[tid] = lofs[tid];
        int node = n0 + tid;
        if (node < N) {
            rowptr[node] = base + lofs[tid];
            dinv[node] = rsqrtf((float)(lcnt[tid] + 1));   // +1 self loop
        }
    }
    __syncthreads();
    for (int i = tid; i < m; i += 256) {
        int p = pk[i];
        int ld = p >> 17, s = p & 131071;
        int r = atomicAdd(&lcur[ld], 1);
        col[base + r] = s;
    }
}

// ---------------- GEMM: chunk-major fp16 table ----------------
// tbl[8][N][32B]: chunk c holds feats [16c, 16c+16) of every node, contiguous.
// Each 3.2 MB slice fits one XCD's 4 MiB L2 -> spmm gathers become L2 hits.

__device__ inline unsigned pack2(float x, float y) {
    __half2 h = __floats2half2_rn(x, y);
    return *(unsigned*)&h;
}

__global__ __launch_bounds__(256) void gemm128_kernel(const float* __restrict__ A,
        const float* __restrict__ W, const float* __restrict__ scale,
        unsigned short* __restrict__ C, int N) {
    __shared__ float As[64][H + 1];
    int tid = threadIdx.x;
    int r0 = blockIdx.x * 64;

    #pragma unroll
    for (int i = 0; i < 8; ++i) {
        int lin = tid + i * 256;          // float4 index, 2048 total
        int r = lin >> 5;                 // 32 float4 per row
        int c4 = (lin & 31) << 2;
        float4 v = make_float4(0.f, 0.f, 0.f, 0.f);
        if (r0 + r < N) v = *(const float4*)&A[(size_t)(r0 + r) * H + c4];
        As[r][c4 + 0] = v.x; As[r][c4 + 1] = v.y;
        As[r][c4 + 2] = v.z; As[r][c4 + 3] = v.w;
    }
    __syncthreads();

    int row = tid & 63;
    int c0 = __builtin_amdgcn_readfirstlane((tid >> 6) << 5);

    float acc[32];
    #pragma unroll
    for (int j = 0; j < 32; ++j) acc[j] = 0.f;

    for (int k = 0; k < H; ++k) {
        float a = As[row][k];
        #pragma unroll
        for (int j = 0; j < 32; ++j)
            acc[j] = fmaf(a, W[k * H + c0 + j], acc[j]);
    }

    int gr = r0 + row;
    if (gr < N) {
        float s = scale[gr];
        uint4* tbl = (uint4*)C;
        int chunkA = c0 >> 4;                         // cols c0..c0+15
        // chunk-major: slice chunk holds uint4[ N*2 ], node's 32B at index node*2
        size_t iA = ((size_t)chunkA * N + gr) * 2;
        size_t iB = ((size_t)(chunkA + 1) * N + gr) * 2;
        uint4 w0, w1;
        w0.x = pack2(acc[0] * s,  acc[1] * s);
        w0.y = pack2(acc[2] * s,  acc[3] * s);
        w0.z = pack2(acc[4] * s,  acc[5] * s);
        w0.w = pack2(acc[6] * s,  acc[7] * s);
        w1.x = pack2(acc[8] * s,  acc[9] * s);
        w1.y = pack2(acc[10] * s, acc[11] * s);
        w1.z = pack2(acc[12] * s, acc[13] * s);
        w1.w = pack2(acc[14] * s, acc[15] * s);
        tbl[iA + 0] = w0;
        tbl[iA + 1] = w1;
        w0.x = pack2(acc[16] * s, acc[17] * s);
        w0.y = pack2(acc[18] * s, acc[19] * s);
        w0.z = pack2(acc[20] * s, acc[21] * s);
        w0.w = pack2(acc[22] * s, acc[23] * s);
        w1.x = pack2(acc[24] * s, acc[25] * s);
        w1.y = pack2(acc[26] * s, acc[27] * s);
        w1.z = pack2(acc[28] * s, acc[29] * s);
        w1.w = pack2(acc[30] * s, acc[31] * s);
        tbl[iB + 0] = w0;
        tbl[iB + 1] = w1;
    }
}

// ---------------- SpMM pull, XCD-sharded features (chunk-major table) ----------------
// chunk = blockIdx.x & 7 -> XCD id (round-robin dispatch). Chunk c's 3.2 MB slice
// lives in XCD c's L2. col reads and fp32 out writes are STREAMS (dead after use):
// nt-hinted so they don't LRU-evict the hot table slice.

__device__ inline void add8(float* a, uint4 v) {
    float2 f;
    f = __half22float2(*(const __half2*)&v.x); a[0] += f.x; a[1] += f.y;
    f = __half22float2(*(const __half2*)&v.y); a[2] += f.x; a[3] += f.y;
    f = __half22float2(*(const __half2*)&v.z); a[4] += f.x; a[5] += f.y;
    f = __half22float2(*(const __half2*)&v.w); a[6] += f.x; a[7] += f.y;
}

__global__ __launch_bounds__(256) void spmm_kernel(const unsigned short* __restrict__ lin,
        const int* __restrict__ rowptr, const int* __restrict__ col,
        const float* __restrict__ dinv, const float* __restrict__ bias,
        float* __restrict__ out, int N) {
    int tid = threadIdx.x;
    int chunk = blockIdx.x & 7;            // -> XCD id (round-robin dispatch)
    int nb = blockIdx.x >> 3;
    int node = nb * 128 + (tid >> 1);
    if (node >= N) return;
    int half = tid & 1;                    // which uint4 of the 32B chunk

    int beg = rowptr[node];
    int end = rowptr[node + 1];

    // slice base for this chunk, in uint4 units
    const uint4* slice = (const uint4*)lin + (size_t)chunk * N * 2 + half;

    float acc[8];
    {
        uint4 sv = slice[(size_t)node * 2];            // self loop (pre-scaled)
        float2 f;
        f = __half22float2(*(const __half2*)&sv.x); acc[0] = f.x; acc[1] = f.y;
        f = __half22float2(*(const __half2*)&sv.y); acc[2] = f.x; acc[3] = f.y;
        f = __half22float2(*(const __half2*)&sv.z); acc[4] = f.x; acc[5] = f.y;
        f = __half22float2(*(const __half2*)&sv.w); acc[6] = f.x; acc[7] = f.y;
    }

    int e = beg;
    for (; e + 4 <= end; e += 4) {
        int s0 = __builtin_nontemporal_load(col + e);
        int s1 = __builtin_nontemporal_load(col + e + 1);
        int s2 = __builtin_nontemporal_load(col + e + 2);
        int s3 = __builtin_nontemporal_load(col + e + 3);
        uint4 v0 = slice[(size_t)s0 * 2];
        uint4 v1 = slice[(size_t)s1 * 2];
        uint4 v2 = slice[(size_t)s2 * 2];
        uint4 v3 = slice[(size_t)s3 * 2];
        add8(acc, v0);
        add8(acc, v1);
        add8(acc, v2);
        add8(acc, v3);
    }
    for (; e < end; ++e) {
        int s0 = __builtin_nontemporal_load(col + e);
        uint4 v = slice[(size_t)s0 * 2];
        add8(acc, v);
    }

    float d = dinv[node];
    int c8 = (chunk << 4) + (half << 3);   // feature offset
    f32x4_t r0, r1;
    r0.x = tanhf(fmaf(acc[0], d, bias[c8 + 0]));
    r0.y = tanhf(fmaf(acc[1], d, bias[c8 + 1]));
    r0.z = tanhf(fmaf(acc[2], d, bias[c8 + 2]));
    r0.w = tanhf(fmaf(acc[3], d, bias[c8 + 3]));
    r1.x = tanhf(fmaf(acc[4], d, bias[c8 + 4]));
    r1.y = tanhf(fmaf(acc[5], d, bias[c8 + 5]));
    r1.z = tanhf(fmaf(acc[6], d, bias[c8 + 6]));
    r1.w = tanhf(fmaf(acc[7], d, bias[c8 + 7]));
    f32x4_t* op = (f32x4_t*)out + (size_t)node * 32 + (c8 >> 2);
    __builtin_nontemporal_store(r0, op);
    __builtin_nontemporal_store(r1, op + 1);
}

// ---------------- Classifier: LDS-tiled, 64 rows/block, 4 groups x 10 cols ----------------

__global__ __launch_bounds__(256) void classifier_kernel(const float* __restrict__ h,
        const float* __restrict__ Wc, const float* __restrict__ bc,
        float* __restrict__ out, int N, int Cout) {
    __shared__ float As[64][H + 1];
    int tid = threadIdx.x;
    int r0 = blockIdx.x * 64;

    #pragma unroll
    for (int i = 0; i < 8; ++i) {
        int lin = tid + i * 256;          // float4 index, 2048 total
        int r = lin >> 5;
        int c4 = (lin & 31) << 2;
        float4 v = make_float4(0.f, 0.f, 0.f, 0.f);
        if (r0 + r < N) v = *(const float4*)&h[(size_t)(r0 + r) * H + c4];
        As[r][c4 + 0] = v.x; As[r][c4 + 1] = v.y;
        As[r][c4 + 2] = v.z; As[r][c4 + 3] = v.w;
    }
    __syncthreads();

    int row = tid & 63;
    int c0 = __builtin_amdgcn_readfirstlane((tid >> 6) * 10);   // 4 groups x 10 cols = 40

    float acc[10];
    #pragma unroll
    for (int j = 0; j < 10; ++j) acc[j] = bc[c0 + j];

    for (int k = 0; k < H; ++k) {
        float a = As[row][k];
        #pragma unroll
        for (int j = 0; j < 10; ++j)
            acc[j] = fmaf(a, Wc[k * Cout + c0 + j], acc[j]);
    }

    int gr = r0 + row;
    if (gr < N) {
        float* orow = out + (size_t)gr * Cout + c0;
        #pragma unroll
        for (int j = 0; j < 10; ++j) orow[j] = acc[j];
    }
}

// ---------------- launch ----------------

extern "C" void kernel_launch(void* const* d_in, const int* in_sizes, int n_in,
                              void* d_out, int out_size, void* d_ws, size_t ws_size,
                              hipStream_t stream) {
    const float* x  = (const float*)d_in[0];
    const int* eidx = (const int*)d_in[1];
    const float* W1 = (const float*)d_in[2];
    const float* b1 = (const float*)d_in[3];
    const float* W2 = (const float*)d_in[4];
    const float* b2 = (const float*)d_in[5];
    const float* W3 = (const float*)d_in[6];
    const float* b3 = (const float*)d_in[7];
    const float* Wc = (const float*)d_in[8];
    const float* bc = (const float*)d_in[9];

    int N    = in_sizes[0] / H;       // 100000
    int E    = in_sizes[1] / 2;       // 3200000
    int Cout = in_sizes[8] / H;       // 40
    int nbk  = (N + 127) >> 7;        // 782 buckets

    const int* srcp = eidx;
    const int* dstp = eidx + E;

    float* out  = (float*)d_out;
    float* hOut = out + (size_t)N * Cout;   // h output region doubles as ping buffer

    char* p = (char*)d_ws;
    float* hAf      = (float*)p;  p += (size_t)N * H * 4;   // fp16 table lives here (half used)
    int*   col      = (int*)p;    p += (size_t)E * 4;
    int*   rowptr   = (int*)p;    p += (size_t)(N + 1) * 4;
    float* dinv     = (float*)p;  p += (size_t)N * 4;
    int*   bFill    = (int*)p;    p += 1024 * 4;
    int*   bBase    = (int*)p;    p += 1024 * 4;
    unsigned short* hA = (unsigned short*)hAf;
    int*   packed   = (int*)hAf;  // aliases hA: consumed by fine_kernel before gemm1 writes hA

    int gg = (N + 63) / 64;
    int gs = ((N + 127) / 128) * 8;   // 782 nodeblocks x 8 feature-chunks (xcd-sharded)
    int gb = (E + 8191) / 8192;

    hipMemsetAsync(bFill, 0, (size_t)nbk * 4, stream);
    bin_kernel<<<gb, 256, 0, stream>>>(srcp, dstp, bFill, packed, E, nbk);
    bscan_kernel<<<1, 1024, 0, stream>>>(bFill, bBase, nbk, E, rowptr + N);
    fine_kernel<<<nbk, 256, 0, stream>>>(packed, bFill, bBase, rowptr, col, dinv, N);

    // layer 1
    gemm128_kernel<<<gg, 256, 0, stream>>>(x, W1, dinv, hA, N);
    spmm_kernel<<<gs, 256, 0, stream>>>(hA, rowptr, col, dinv, b1, hOut, N);
    // layer 2
    gemm128_kernel<<<gg, 256, 0, stream>>>(hOut, W2, dinv, hA, N);
    spmm_kernel<<<gs, 256, 0, stream>>>(hA, rowptr, col, dinv, b2, hOut, N);
    // layer 3
    gemm128_kernel<<<gg, 256, 0, stream>>>(hOut, W3, dinv, hA, N);
    spmm_kernel<<<gs, 256, 0, stream>>>(hA, rowptr, col, dinv, b3, hOut, N);
    // classifier
    classifier_kernel<<<gg, 256, 0, stream>>>(hOut, Wc, bc, out, N, Cout);
}

// Round 6
// 800.635 us; speedup vs baseline: 1.5849x; 1.5849x over previous
//
#include <hip/hip_runtime.h>
#include <hip/hip_fp16.h>
#include <math.h>

#define H 128
#define BSTRIDE 5120            // packed entries per bucket (mean 4096, +16 sigma)
#define NPH 25                  // src phases: src>>12 -> 0..24 (~4096 nodes = 1 MB slice)

// ---------------- CSR build: bucketed counting sort ----------------
// bucket = dst >> 7 (128 nodes per bucket). packed entry = (local_dst<<17)|src.

__global__ __launch_bounds__(256) void bin_kernel(const int* __restrict__ src,
        const int* __restrict__ dst, int* __restrict__ bucketFill,
        int* __restrict__ packed, int E, int nbk) {
    __shared__ int hcnt[1024];
    __shared__ int base[1024];
    __shared__ int cur[1024];
    int tid = threadIdx.x;
    for (int i = tid; i < nbk; i += 256) { hcnt[i] = 0; cur[i] = 0; }
    __syncthreads();
    int e0 = blockIdx.x * 8192;
    int e1 = min(e0 + 8192, E);
    for (int e = e0 + tid; e < e1; e += 256)
        atomicAdd(&hcnt[dst[e] >> 7], 1);
    __syncthreads();
    for (int i = tid; i < nbk; i += 256) {
        int c = hcnt[i];
        base[i] = c ? atomicAdd(&bucketFill[i], c) : 0;   // claim contiguous chunk
    }
    __syncthreads();
    for (int e = e0 + tid; e < e1; e += 256) {
        int d = dst[e], s = src[e];
        int b = d >> 7;
        int r = atomicAdd(&cur[b], 1);
        packed[b * BSTRIDE + base[b] + r] = ((d & 127) << 17) | s;
    }
}

__global__ void bscan_kernel(const int* __restrict__ bucketFill, int* __restrict__ bucketBase,
                             int nbk, int E, int* __restrict__ rowptrN) {
    __shared__ int s[1024];
    int t = threadIdx.x;
    int v0 = (t < nbk) ? bucketFill[t] : 0;
    s[t] = v0;
    __syncthreads();
    for (int off = 1; off < 1024; off <<= 1) {
        int v = 0;
        if (t >= off) v = s[t - off];
        __syncthreads();
        s[t] += v;
        __syncthreads();
    }
    bucketBase[t] = s[t] - v0;                 // exclusive
    if (t == 0) rowptrN[0] = E;                // rowptr[N] = E
}

// fine_kernel: per-node CSR ranges with edges SORTED BY SRC PHASE (src>>12).
// All spmm threads then sweep src ranges in near-lockstep -> the chip-wide
// instantaneous gather working set is ~1-3 MB (vs 25.6 MB unsorted), so each
// L2 retains the active slice and table rows are fetched ~once per sweep.
__global__ __launch_bounds__(256) void fine_kernel(const int* __restrict__ packed,
        const int* __restrict__ bucketFill, const int* __restrict__ bucketBase,
        int* __restrict__ rowptr, int* __restrict__ col, float* __restrict__ dinv, int N) {
    __shared__ int cnt[128 * NPH];     // 12.8 KB: per (local_dst, phase) count
    __shared__ int cur[128 * NPH];     // 12.8 KB: running scatter cursor
    __shared__ int lcnt[128], lofs[128];
    int b = blockIdx.x;
    int tid = threadIdx.x;
    int m = bucketFill[b]; if (m > BSTRIDE) m = BSTRIDE;
    int base = bucketBase[b];
    int n0 = b << 7;
    for (int i = tid; i < 128 * NPH; i += 256) cnt[i] = 0;
    __syncthreads();
    const int* pk = packed + (size_t)b * BSTRIDE;
    for (int i = tid; i < m; i += 256) {
        int p = pk[i];
        int ld = p >> 17, s = p & 131071;
        atomicAdd(&cnt[ld * NPH + (s >> 12)], 1);
    }
    __syncthreads();
    if (tid < 128) {
        int t = 0;
        #pragma unroll
        for (int q = 0; q < NPH; ++q) t += cnt[tid * NPH + q];
        lcnt[tid] = t;
    }
    __syncthreads();
    if (tid == 0) {
        int acc = 0;
        #pragma unroll 4
        for (int i = 0; i < 128; ++i) { lofs[i] = acc; acc += lcnt[i]; }
    }
    __syncthreads();
    if (tid < 128) {
        int o = lofs[tid];
        #pragma unroll
        for (int q = 0; q < NPH; ++q) {
            int c = cnt[tid * NPH + q];
            cur[tid * NPH + q] = o;
            o += c;
        }
        int node = n0 + tid;
        if (node < N) {
            rowptr[node] = base + lofs[tid];
            dinv[node] = rsqrtf((float)(lcnt[tid] + 1));   // +1 self loop
        }
    }
    __syncthreads();
    for (int i = tid; i < m; i += 256) {
        int p = pk[i];
        int ld = p >> 17, s = p & 131071;
        int r = atomicAdd(&cur[ld * NPH + (s >> 12)], 1);
        col[base + r] = s;
    }
}

// ---------------- GEMM: C[n,128] = fp16((A[n,128] @ W[128,128]) * scale[n]) ----------------

__device__ inline unsigned pack2(float x, float y) {
    __half2 h = __floats2half2_rn(x, y);
    return *(unsigned*)&h;
}

__global__ __launch_bounds__(256) void gemm128_kernel(const float* __restrict__ A,
        const float* __restrict__ W, const float* __restrict__ scale,
        unsigned short* __restrict__ C, int N) {
    __shared__ float As[64][H + 1];
    int tid = threadIdx.x;
    int r0 = blockIdx.x * 64;

    #pragma unroll
    for (int i = 0; i < 8; ++i) {
        int lin = tid + i * 256;          // float4 index, 2048 total
        int r = lin >> 5;                 // 32 float4 per row
        int c4 = (lin & 31) << 2;
        float4 v = make_float4(0.f, 0.f, 0.f, 0.f);
        if (r0 + r < N) v = *(const float4*)&A[(size_t)(r0 + r) * H + c4];
        As[r][c4 + 0] = v.x; As[r][c4 + 1] = v.y;
        As[r][c4 + 2] = v.z; As[r][c4 + 3] = v.w;
    }
    __syncthreads();

    int row = tid & 63;
    int c0 = __builtin_amdgcn_readfirstlane((tid >> 6) << 5);

    float acc[32];
    #pragma unroll
    for (int j = 0; j < 32; ++j) acc[j] = 0.f;

    for (int k = 0; k < H; ++k) {
        float a = As[row][k];
        #pragma unroll
        for (int j = 0; j < 32; ++j)
            acc[j] = fmaf(a, W[k * H + c0 + j], acc[j]);
    }

    int gr = r0 + row;
    if (gr < N) {
        float s = scale[gr];
        unsigned short* Crow = C + (size_t)gr * H;
        #pragma unroll
        for (int j = 0; j < 32; j += 8) {
            uint4 w;
            w.x = pack2(acc[j + 0] * s, acc[j + 1] * s);
            w.y = pack2(acc[j + 2] * s, acc[j + 3] * s);
            w.z = pack2(acc[j + 4] * s, acc[j + 5] * s);
            w.w = pack2(acc[j + 6] * s, acc[j + 7] * s);
            *(uint4*)&Crow[c0 + j] = w;
        }
    }
}

// ---------------- SpMM pull (fp16 gather table, fp32 accumulate/output) ----------------
// 16 threads/node, each owns 8 features (one 16B uint4 of the 256B fp16 row).

__device__ inline void add8(float* a, uint4 v) {
    float2 f;
    f = __half22float2(*(const __half2*)&v.x); a[0] += f.x; a[1] += f.y;
    f = __half22float2(*(const __half2*)&v.y); a[2] += f.x; a[3] += f.y;
    f = __half22float2(*(const __half2*)&v.z); a[4] += f.x; a[5] += f.y;
    f = __half22float2(*(const __half2*)&v.w); a[6] += f.x; a[7] += f.y;
}

__global__ __launch_bounds__(256) void spmm_kernel(const unsigned short* __restrict__ lin,
        const int* __restrict__ rowptr, const int* __restrict__ col,
        const float* __restrict__ dinv, const float* __restrict__ bias,
        float* __restrict__ out, int N) {
    int tid = threadIdx.x;
    int node = blockIdx.x * 16 + (tid >> 4);
    if (node >= N) return;
    int cq = tid & 15;                                 // 16B chunk within row

    int beg = rowptr[node];
    int end = rowptr[node + 1];

    const uint4* linv = (const uint4*)lin;

    float acc[8];
    {
        uint4 sv = linv[(size_t)node * 16 + cq];       // self loop (pre-scaled)
        float2 f;
        f = __half22float2(*(const __half2*)&sv.x); acc[0] = f.x; acc[1] = f.y;
        f = __half22float2(*(const __half2*)&sv.y); acc[2] = f.x; acc[3] = f.y;
        f = __half22float2(*(const __half2*)&sv.z); acc[4] = f.x; acc[5] = f.y;
        f = __half22float2(*(const __half2*)&sv.w); acc[6] = f.x; acc[7] = f.y;
    }

    int e = beg;
    for (; e + 4 <= end; e += 4) {
        int s0 = col[e], s1 = col[e + 1], s2 = col[e + 2], s3 = col[e + 3];
        uint4 v0 = linv[(size_t)s0 * 16 + cq];
        uint4 v1 = linv[(size_t)s1 * 16 + cq];
        uint4 v2 = linv[(size_t)s2 * 16 + cq];
        uint4 v3 = linv[(size_t)s3 * 16 + cq];
        add8(acc, v0);
        add8(acc, v1);
        add8(acc, v2);
        add8(acc, v3);
    }
    for (; e < end; ++e) {
        uint4 v = linv[(size_t)col[e] * 16 + cq];
        add8(acc, v);
    }

    float d = dinv[node];
    int c8 = cq << 3;
    float4 r0, r1;
    r0.x = tanhf(fmaf(acc[0], d, bias[c8 + 0]));
    r0.y = tanhf(fmaf(acc[1], d, bias[c8 + 1]));
    r0.z = tanhf(fmaf(acc[2], d, bias[c8 + 2]));
    r0.w = tanhf(fmaf(acc[3], d, bias[c8 + 3]));
    r1.x = tanhf(fmaf(acc[4], d, bias[c8 + 4]));
    r1.y = tanhf(fmaf(acc[5], d, bias[c8 + 5]));
    r1.z = tanhf(fmaf(acc[6], d, bias[c8 + 6]));
    r1.w = tanhf(fmaf(acc[7], d, bias[c8 + 7]));
    float4* op = (float4*)out + (size_t)node * 32 + (cq << 1);
    op[0] = r0;
    op[1] = r1;
}

// ---------------- Classifier: LDS-tiled, 64 rows/block, 4 groups x 10 cols ----------------

__global__ __launch_bounds__(256) void classifier_kernel(const float* __restrict__ h,
        const float* __restrict__ Wc, const float* __restrict__ bc,
        float* __restrict__ out, int N, int Cout) {
    __shared__ float As[64][H + 1];
    int tid = threadIdx.x;
    int r0 = blockIdx.x * 64;

    #pragma unroll
    for (int i = 0; i < 8; ++i) {
        int lin = tid + i * 256;          // float4 index, 2048 total
        int r = lin >> 5;
        int c4 = (lin & 31) << 2;
        float4 v = make_float4(0.f, 0.f, 0.f, 0.f);
        if (r0 + r < N) v = *(const float4*)&h[(size_t)(r0 + r) * H + c4];
        As[r][c4 + 0] = v.x; As[r][c4 + 1] = v.y;
        As[r][c4 + 2] = v.z; As[r][c4 + 3] = v.w;
    }
    __syncthreads();

    int row = tid & 63;
    int c0 = __builtin_amdgcn_readfirstlane((tid >> 6) * 10);   // 4 groups x 10 cols = 40

    float acc[10];
    #pragma unroll
    for (int j = 0; j < 10; ++j) acc[j] = bc[c0 + j];

    for (int k = 0; k < H; ++k) {
        float a = As[row][k];
        #pragma unroll
        for (int j = 0; j < 10; ++j)
            acc[j] = fmaf(a, Wc[k * Cout + c0 + j], acc[j]);
    }

    int gr = r0 + row;
    if (gr < N) {
        float* orow = out + (size_t)gr * Cout + c0;
        #pragma unroll
        for (int j = 0; j < 10; ++j) orow[j] = acc[j];
    }
}

// ---------------- launch ----------------

extern "C" void kernel_launch(void* const* d_in, const int* in_sizes, int n_in,
                              void* d_out, int out_size, void* d_ws, size_t ws_size,
                              hipStream_t stream) {
    const float* x  = (const float*)d_in[0];
    const int* eidx = (const int*)d_in[1];
    const float* W1 = (const float*)d_in[2];
    const float* b1 = (const float*)d_in[3];
    const float* W2 = (const float*)d_in[4];
    const float* b2 = (const float*)d_in[5];
    const float* W3 = (const float*)d_in[6];
    const float* b3 = (const float*)d_in[7];
    const float* Wc = (const float*)d_in[8];
    const float* bc = (const float*)d_in[9];

    int N    = in_sizes[0] / H;       // 100000
    int E    = in_sizes[1] / 2;       // 3200000
    int Cout = in_sizes[8] / H;       // 40
    int nbk  = (N + 127) >> 7;        // 782 buckets

    const int* srcp = eidx;
    const int* dstp = eidx + E;

    float* out  = (float*)d_out;
    float* hOut = out + (size_t)N * Cout;   // h output region doubles as ping buffer

    char* p = (char*)d_ws;
    float* hAf      = (float*)p;  p += (size_t)N * H * 4;   // fp16 table lives here (half used)
    int*   col      = (int*)p;    p += (size_t)E * 4;
    int*   rowptr   = (int*)p;    p += (size_t)(N + 1) * 4;
    float* dinv     = (float*)p;  p += (size_t)N * 4;
    int*   bFill    = (int*)p;    p += 1024 * 4;
    int*   bBase    = (int*)p;    p += 1024 * 4;
    unsigned short* hA = (unsigned short*)hAf;
    int*   packed   = (int*)hAf;  // aliases hA: consumed by fine_kernel before gemm1 writes hA

    int gg = (N + 63) / 64;
    int gs = (N + 15) / 16;
    int gb = (E + 8191) / 8192;

    hipMemsetAsync(bFill, 0, (size_t)nbk * 4, stream);
    bin_kernel<<<gb, 256, 0, stream>>>(srcp, dstp, bFill, packed, E, nbk);
    bscan_kernel<<<1, 1024, 0, stream>>>(bFill, bBase, nbk, E, rowptr + N);
    fine_kernel<<<nbk, 256, 0, stream>>>(packed, bFill, bBase, rowptr, col, dinv, N);

    // layer 1
    gemm128_kernel<<<gg, 256, 0, stream>>>(x, W1, dinv, hA, N);
    spmm_kernel<<<gs, 256, 0, stream>>>(hA, rowptr, col, dinv, b1, hOut, N);
    // layer 2
    gemm128_kernel<<<gg, 256, 0, stream>>>(hOut, W2, dinv, hA, N);
    spmm_kernel<<<gs, 256, 0, stream>>>(hA, rowptr, col, dinv, b2, hOut, N);
    // layer 3
    gemm128_kernel<<<gg, 256, 0, stream>>>(hOut, W3, dinv, hA, N);
    spmm_kernel<<<gs, 256, 0, stream>>>(hA, rowptr, col, dinv, b3, hOut, N);
    // classifier
    classifier_kernel<<<gg, 256, 0, stream>>>(hOut, Wc, bc, out, N, Cout);
}